// Round 2
// baseline (36405.670 us; speedup 1.0000x reference)
//
#include <hip/hip_runtime.h>

#define S_LEN 4096
#define BATCH 16
#define HID   256     // H == F == 256
#define GATE4 1024    // 4F

typedef __bf16 bf16x8 __attribute__((ext_vector_type(8)));
typedef float  f32x4  __attribute__((ext_vector_type(4)));

union FragU {
    unsigned short u[8];
    bf16x8 v;
    uint4  q;
};

__device__ __forceinline__ unsigned short f2bf(float f) {
    unsigned u = __builtin_bit_cast(unsigned, f);
    u += 0x7fffu + ((u >> 16) & 1u);
    return (unsigned short)(u >> 16);
}
__device__ __forceinline__ float bf2f(unsigned short s) {
    unsigned u = ((unsigned)s) << 16;
    return __builtin_bit_cast(float, u);
}
// rcp-based fast gates: v_exp_f32 + v_rcp_f32, no IEEE div expansion
__device__ __forceinline__ float fsigmoid(float x) {
    return __builtin_amdgcn_rcpf(1.f + __expf(-x));
}
__device__ __forceinline__ float ftanh(float x) {
    float e = __expf(2.f * x);            // +/-inf-safe: e->inf => 1-0, e->0 => -1
    return 1.f - 2.f * __builtin_amdgcn_rcpf(e + 1.f);
}

// ---------------------------------------------------------------------------
// Kernel 1: xp[d][s][b][j] = (sum_k x[b][t_eff][k] * Wi_d[k][j]) + bias_d[j]
// stored as bf16. M = S*B = 65536 (row r = t*16+b), K = 256, N = 1024 per dir.
// ---------------------------------------------------------------------------
__global__ __launch_bounds__(256, 2) void xp_gemm(
    const float* __restrict__ X,       // inputs [B][S][H]
    const float* __restrict__ Wi_fw, const float* __restrict__ b_fw,
    const float* __restrict__ Wi_rv, const float* __restrict__ b_rv,
    unsigned short* __restrict__ xp_fw, unsigned short* __restrict__ xp_rv)
{
    const int dir = blockIdx.z;
    const float* Wi   = dir ? Wi_rv : Wi_fw;
    const float* bias = dir ? b_rv  : b_fw;
    unsigned short* xp = dir ? xp_rv : xp_fw;

    __shared__ unsigned short As[64][40];   // [m][k] bf16, padded pitch
    __shared__ unsigned short Bs[64][40];   // [n][k] bf16 (transposed), padded

    const int tid  = threadIdx.x;
    const int lane = tid & 63;
    const int wid  = tid >> 6;       // 0..3
    const int quad = lane >> 4;      // 0..3
    const int l16  = lane & 15;
    const int wm = wid >> 1, wn = wid & 1;

    const int r0 = blockIdx.x * 64;  // M block
    const int n0 = blockIdx.y * 64;  // N block within 1024

    const int ai = tid & 63;             // A tile row
    const int ak = (tid >> 6) * 8;       // A k offset {0,8,16,24}
    const int bk = tid >> 3;             // B k row 0..31
    const int bj = (tid & 7) * 8;        // B n offset

    const int r  = r0 + ai;
    const int t  = r >> 4, bb = r & 15;
    const int t_eff = dir ? (S_LEN - 1 - t) : t;
    const float* Arow = X + ((size_t)bb * S_LEN + t_eff) * HID;

    f32x4 acc[2][2];
    #pragma unroll
    for (int i = 0; i < 2; ++i)
        #pragma unroll
        for (int j = 0; j < 2; ++j) { acc[i][j][0]=0.f; acc[i][j][1]=0.f; acc[i][j][2]=0.f; acc[i][j][3]=0.f; }

    for (int kb = 0; kb < HID / 32; ++kb) {
        {
            const float* p = Arow + kb * 32 + ak;
            float4 v0 = *(const float4*)p;
            float4 v1 = *(const float4*)(p + 4);
            FragU fu;
            fu.u[0]=f2bf(v0.x); fu.u[1]=f2bf(v0.y); fu.u[2]=f2bf(v0.z); fu.u[3]=f2bf(v0.w);
            fu.u[4]=f2bf(v1.x); fu.u[5]=f2bf(v1.y); fu.u[6]=f2bf(v1.z); fu.u[7]=f2bf(v1.w);
            *(uint4*)&As[ai][ak] = fu.q;
        }
        {
            const float* p = Wi + (size_t)(kb * 32 + bk) * GATE4 + n0 + bj;
            float4 v0 = *(const float4*)p;
            float4 v1 = *(const float4*)(p + 4);
            unsigned short tmp[8] = { f2bf(v0.x), f2bf(v0.y), f2bf(v0.z), f2bf(v0.w),
                                      f2bf(v1.x), f2bf(v1.y), f2bf(v1.z), f2bf(v1.w) };
            #pragma unroll
            for (int jj = 0; jj < 8; ++jj) Bs[bj + jj][bk] = tmp[jj];
        }
        __syncthreads();

        bf16x8 a0 = *(const bf16x8*)&As[wm * 32 + l16][quad * 8];
        bf16x8 a1 = *(const bf16x8*)&As[wm * 32 + 16 + l16][quad * 8];
        bf16x8 B0 = *(const bf16x8*)&Bs[wn * 32 + l16][quad * 8];
        bf16x8 B1 = *(const bf16x8*)&Bs[wn * 32 + 16 + l16][quad * 8];
        acc[0][0] = __builtin_amdgcn_mfma_f32_16x16x32_bf16(a0, B0, acc[0][0], 0, 0, 0);
        acc[0][1] = __builtin_amdgcn_mfma_f32_16x16x32_bf16(a0, B1, acc[0][1], 0, 0, 0);
        acc[1][0] = __builtin_amdgcn_mfma_f32_16x16x32_bf16(a1, B0, acc[1][0], 0, 0, 0);
        acc[1][1] = __builtin_amdgcn_mfma_f32_16x16x32_bf16(a1, B1, acc[1][1], 0, 0, 0);
        __syncthreads();
    }

    #pragma unroll
    for (int am = 0; am < 2; ++am)
        #pragma unroll
        for (int bn = 0; bn < 2; ++bn) {
            int ncol = n0 + wn * 32 + bn * 16 + l16;
            float bv = bias[ncol];
            #pragma unroll
            for (int rr = 0; rr < 4; ++rr) {
                int rrow = r0 + wm * 32 + am * 16 + quad * 4 + rr;
                float v = acc[am][bn][rr] + bv;
                xp[(size_t)rrow * GATE4 + ncol] = f2bf(v);
            }
        }
}

// ---------------------------------------------------------------------------
// Kernel 2: recurrence. 4 WGs (dir, half). Exchange = tagged 8-byte chunks
// [h_lo16 | h_hi16 | tag32], relaxed agent atomics only. No fences, no
// acquire/release (avoids buffer_wbl2 / buffer_inv per step). Split-K: own
// half MFMAs issue before the partner poll; xp prefetched one step ahead.
// ---------------------------------------------------------------------------
__global__ __launch_bounds__(512, 2) void lstm_rec(
    const float* __restrict__ Wh_fw, const float* __restrict__ Wh_rv,
    const unsigned short* __restrict__ xp_fw, const unsigned short* __restrict__ xp_rv,
    float* __restrict__ out,                  // [B][S][512]
    float* __restrict__ finals,               // c_fw,h_fw,c_rv,h_rv (each 16x256)
    unsigned long long* __restrict__ exch)    // [dir][parity][half][1024] chunks
{
    const int wgid = blockIdx.x;        // 0..3
    const int dir  = wgid >> 1;
    const int half = wgid & 1;
    const float* Wh = dir ? Wh_rv : Wh_fw;
    const unsigned short* xp = dir ? xp_rv : xp_fw;

    const int tid  = threadIdx.x;
    const int lane = tid & 63;
    const int wid  = tid >> 6;          // 0..7
    const int quad = lane >> 4;
    const int l16  = lane & 15;

    const int fbase = half * 128 + wid * 16;   // dir-local f of this wave's block
    const int pf    = (1 - half) * 128 + wid * 16 + l16;  // partner write slot in hbuf

    __shared__ unsigned short hbuf[16][264];   // full h (bf16), padded pitch

    for (int i = tid; i < 16 * 264; i += 512) ((unsigned short*)hbuf)[i] = 0;

    // Wh B-fragments (resident): Bfrag[g][kt], lane holds
    // Wh[k = kt*32 + quad*8 + j][g*256 + fbase + l16], j=0..7.
    bf16x8 Bfrag[4][8];
    #pragma unroll
    for (int g = 0; g < 4; ++g) {
        int col = g * 256 + fbase + l16;
        #pragma unroll
        for (int kt = 0; kt < 8; ++kt) {
            FragU fu;
            #pragma unroll
            for (int j = 0; j < 8; ++j) {
                int k = kt * 32 + quad * 8 + j;
                fu.u[j] = f2bf(Wh[(size_t)k * GATE4 + col]);
            }
            Bfrag[g][kt] = fu.v;
        }
    }

    float cst[4]  = {0.f, 0.f, 0.f, 0.f};
    float hval[4] = {0.f, 0.f, 0.f, 0.f};
    __syncthreads();

    // xp prefetch for step 0
    float xpz[4][4];
    {
        const unsigned short* xprow = xp;
        #pragma unroll
        for (int g = 0; g < 4; ++g)
            #pragma unroll
            for (int rr = 0; rr < 4; ++rr)
                xpz[g][rr] = bf2f(xprow[(quad * 4 + rr) * GATE4 + g * 256 + fbase + l16]);
    }

    const int own_kt0 = half * 4;          // own-half K tiles (h we compute locally)
    const int par_kt0 = (1 - half) * 4;    // partner-half K tiles

    for (int s = 0; s < S_LEN; ++s) {
        // --- own-half K MFMAs (h_{s-1} own half already in LDS) ---
        f32x4 accg[4];
        #pragma unroll
        for (int g = 0; g < 4; ++g) { accg[g][0]=0.f; accg[g][1]=0.f; accg[g][2]=0.f; accg[g][3]=0.f; }
        #pragma unroll
        for (int i = 0; i < 4; ++i) {
            bf16x8 a = *(const bf16x8*)&hbuf[l16][(own_kt0 + i) * 32 + quad * 8];
            accg[0] = __builtin_amdgcn_mfma_f32_16x16x32_bf16(a, Bfrag[0][own_kt0 + i], accg[0], 0, 0, 0);
            accg[1] = __builtin_amdgcn_mfma_f32_16x16x32_bf16(a, Bfrag[1][own_kt0 + i], accg[1], 0, 0, 0);
            accg[2] = __builtin_amdgcn_mfma_f32_16x16x32_bf16(a, Bfrag[2][own_kt0 + i], accg[2], 0, 0, 0);
            accg[3] = __builtin_amdgcn_mfma_f32_16x16x32_bf16(a, Bfrag[3][own_kt0 + i], accg[3], 0, 0, 0);
        }

        // --- receive partner h_{s-1}: poll tagged chunks (tag == s) ---
        if (s > 0) {
            unsigned long long* psl = exch +
                ((size_t)((dir * 2 + ((s - 1) & 1)) * 2 + (1 - half)) * 1024) + tid * 2;
            const unsigned tag = (unsigned)s;
            unsigned long long v0 = __hip_atomic_load(psl,     __ATOMIC_RELAXED, __HIP_MEMORY_SCOPE_AGENT);
            unsigned long long v1 = __hip_atomic_load(psl + 1, __ATOMIC_RELAXED, __HIP_MEMORY_SCOPE_AGENT);
            while ((unsigned)(v0 >> 32) != tag)
                v0 = __hip_atomic_load(psl,     __ATOMIC_RELAXED, __HIP_MEMORY_SCOPE_AGENT);
            while ((unsigned)(v1 >> 32) != tag)
                v1 = __hip_atomic_load(psl + 1, __ATOMIC_RELAXED, __HIP_MEMORY_SCOPE_AGENT);
            hbuf[quad * 4 + 0][pf] = (unsigned short)(v0 & 0xffffu);
            hbuf[quad * 4 + 1][pf] = (unsigned short)((v0 >> 16) & 0xffffu);
            hbuf[quad * 4 + 2][pf] = (unsigned short)(v1 & 0xffffu);
            hbuf[quad * 4 + 3][pf] = (unsigned short)((v1 >> 16) & 0xffffu);
        }
        __syncthreads();   // partner half visible; own-half reads done before overwrite

        // --- partner-half K MFMAs ---
        #pragma unroll
        for (int i = 0; i < 4; ++i) {
            bf16x8 a = *(const bf16x8*)&hbuf[l16][(par_kt0 + i) * 32 + quad * 8];
            accg[0] = __builtin_amdgcn_mfma_f32_16x16x32_bf16(a, Bfrag[0][par_kt0 + i], accg[0], 0, 0, 0);
            accg[1] = __builtin_amdgcn_mfma_f32_16x16x32_bf16(a, Bfrag[1][par_kt0 + i], accg[1], 0, 0, 0);
            accg[2] = __builtin_amdgcn_mfma_f32_16x16x32_bf16(a, Bfrag[2][par_kt0 + i], accg[2], 0, 0, 0);
            accg[3] = __builtin_amdgcn_mfma_f32_16x16x32_bf16(a, Bfrag[3][par_kt0 + i], accg[3], 0, 0, 0);
        }

        // --- gates ---
        unsigned short hb[4];
        #pragma unroll
        for (int rr = 0; rr < 4; ++rr) {
            float zi = accg[0][rr] + xpz[0][rr];
            float zf = accg[1][rr] + xpz[1][rr];
            float zg = accg[2][rr] + xpz[2][rr];
            float zo = accg[3][rr] + xpz[3][rr];
            float c  = fsigmoid(zf) * cst[rr] + fsigmoid(zi) * ftanh(zg);
            cst[rr]  = c;
            hval[rr] = fsigmoid(zo) * ftanh(c);
            hb[rr]   = f2bf(hval[rr]);
        }

        // --- publish own h_s (tag s+1), fire-and-forget ---
        if (s < S_LEN - 1) {
            unsigned long long* msl = exch +
                ((size_t)((dir * 2 + (s & 1)) * 2 + half) * 1024) + tid * 2;
            unsigned long long t64 = ((unsigned long long)(unsigned)(s + 1)) << 32;
            unsigned long long c0 = t64 | ((unsigned)hb[1] << 16) | (unsigned)hb[0];
            unsigned long long c1 = t64 | ((unsigned)hb[3] << 16) | (unsigned)hb[2];
            __hip_atomic_store(msl,     c0, __ATOMIC_RELAXED, __HIP_MEMORY_SCOPE_AGENT);
            __hip_atomic_store(msl + 1, c1, __ATOMIC_RELAXED, __HIP_MEMORY_SCOPE_AGENT);
        }

        // --- own half -> LDS ---
        #pragma unroll
        for (int rr = 0; rr < 4; ++rr)
            hbuf[quad * 4 + rr][fbase + l16] = hb[rr];

        // --- xp prefetch for s+1 (latency hides behind out-store/sync/poll) ---
        float xpn[4][4];
        if (s < S_LEN - 1) {
            const unsigned short* xprow = xp + (size_t)(s + 1) * BATCH * GATE4;
            #pragma unroll
            for (int g = 0; g < 4; ++g)
                #pragma unroll
                for (int rr = 0; rr < 4; ++rr)
                    xpn[g][rr] = bf2f(xprow[(quad * 4 + rr) * GATE4 + g * 256 + fbase + l16]);
        }

        // --- fp32 output (off critical path) ---
        {
            int t_orig = dir ? (S_LEN - 1 - s) : s;
            #pragma unroll
            for (int rr = 0; rr < 4; ++rr) {
                int m = quad * 4 + rr;
                out[((size_t)m * S_LEN + t_orig) * 512 + dir * 256 + fbase + l16] = hval[rr];
            }
        }

        __syncthreads();   // own-half LDS writes complete before next step's reads

        #pragma unroll
        for (int g = 0; g < 4; ++g)
            #pragma unroll
            for (int rr = 0; rr < 4; ++rr)
                xpz[g][rr] = xpn[g][rr];
    }

    // final states: c then h, fw block then rv block
    {
        float* cdst = finals + (dir ? 8192 : 0);
        float* hdst = cdst + 4096;
        #pragma unroll
        for (int rr = 0; rr < 4; ++rr) {
            int m = quad * 4 + rr;
            int f = fbase + l16;
            cdst[m * 256 + f] = cst[rr];
            hdst[m * 256 + f] = hval[rr];
        }
    }
}

// ---------------------------------------------------------------------------
extern "C" void kernel_launch(void* const* d_in, const int* in_sizes, int n_in,
                              void* d_out, int out_size, void* d_ws, size_t ws_size,
                              hipStream_t stream)
{
    const float* X     = (const float*)d_in[0];
    const float* Wi_fw = (const float*)d_in[1];
    const float* Wh_fw = (const float*)d_in[2];
    const float* b_fw  = (const float*)d_in[3];
    const float* Wi_rv = (const float*)d_in[4];
    const float* Wh_rv = (const float*)d_in[5];
    const float* b_rv  = (const float*)d_in[6];

    float* out    = (float*)d_out;
    float* finals = out + (size_t)BATCH * S_LEN * 512;

    char* ws = (char*)d_ws;
    unsigned short* xp_fw = (unsigned short*)ws;                          // 128 MiB
    unsigned short* xp_rv = (unsigned short*)(ws + 134217728ull);         // 128 MiB
    unsigned long long* exch = (unsigned long long*)(ws + 268435456ull);  // 64 KiB
    // tag scheme: 0xAAAAAAAA poison never equals a step tag (1..4095) -> no init needed

    dim3 g(65536 / 64, 1024 / 64, 2);
    xp_gemm<<<g, 256, 0, stream>>>(X, Wi_fw, b_fw, Wi_rv, b_rv, xp_fw, xp_rv);

    lstm_rec<<<4, 512, 0, stream>>>(Wh_fw, Wh_rv, xp_fw, xp_rv, out, finals, exch);
}